// Round 5
// baseline (330.689 us; speedup 1.0000x reference)
//
#include <hip/hip_runtime.h>
#include <math.h>

// R3 (resubmit after broker timeout): commute GEMM1 past the layer-1 aggregation.
//   old: h1 = x@W1^T (20.5 MB) -> gather 1 KB/edge (154 MB L2-miss, 57 us)
//   new: gather x (256 B/edge, x=5 MB L2-resident) into per-head ax[N,8,128],
//        then grouped GEMM ax@W1^T with bias+relu fused. h1 never materialized;
//        scores come from x @ (W1^T att) precomputed vectors.
// Also: pool fused into agg2 epilogue (r2 eliminated).

#define NEG_SLOPE 0.2f

using bf16x8 = __attribute__((ext_vector_type(8))) __bf16;
using f32x4  = __attribute__((ext_vector_type(4))) float;

// ---------- bf16 helpers ----------
__device__ __forceinline__ ushort f2bf(float f) {
    unsigned u = __float_as_uint(f);
    unsigned r = (u + 0x7FFFu + ((u >> 16) & 1u)) >> 16;   // RNE
    return (ushort)r;
}
__device__ __forceinline__ unsigned pack2(float a, float b) {
    return (unsigned)f2bf(a) | ((unsigned)f2bf(b) << 16);
}
__device__ __forceinline__ void unpack8(uint4 u, float* f) {
    f[0] = __uint_as_float(u.x << 16); f[1] = __uint_as_float(u.x & 0xFFFF0000u);
    f[2] = __uint_as_float(u.y << 16); f[3] = __uint_as_float(u.y & 0xFFFF0000u);
    f[4] = __uint_as_float(u.z << 16); f[5] = __uint_as_float(u.z & 0xFFFF0000u);
    f[6] = __uint_as_float(u.w << 16); f[7] = __uint_as_float(u.w & 0xFFFF0000u);
}
__device__ __forceinline__ void unpack4(uint2 u, float* f) {
    f[0] = __uint_as_float(u.x << 16); f[1] = __uint_as_float(u.x & 0xFFFF0000u);
    f[2] = __uint_as_float(u.y << 16); f[3] = __uint_as_float(u.y & 0xFFFF0000u);
}

// ---------------- fp32 -> bf16 convert ----------------
__global__ __launch_bounds__(256) void cvt_bf16(const float* __restrict__ in,
                                                ushort* __restrict__ out, int n4) {
    int i = blockIdx.x * 256 + threadIdx.x;
    if (i >= n4) return;
    float4 v = ((const float4*)in)[i];
    uint2 o;
    o.x = pack2(v.x, v.y);
    o.y = pack2(v.z, v.w);
    ((uint2*)out)[i] = o;
}

// ---------------- prep: v_s/v_d[h,f] = sum_c att[h,c] * W1[h*64+c, f] ----------
__global__ __launch_bounds__(256) void prep_v(const float* __restrict__ W1,
                                              const float* __restrict__ att_s,
                                              const float* __restrict__ att_d,
                                              float* __restrict__ v_s,
                                              float* __restrict__ v_d) {
    int tid = blockIdx.x * 256 + threadIdx.x;   // 1024 total
    int h = tid >> 7, f = tid & 127;
    float as = 0.f, ad = 0.f;
    for (int c = 0; c < 64; ++c) {
        float w = W1[(size_t)(h * 64 + c) * 128 + f];
        as += att_s[h * 64 + c] * w;
        ad += att_d[h * 64 + c] * w;
    }
    v_s[tid] = as;
    v_d[tid] = ad;
}

// ---------------- layer-1 scores from x: a1s/a1d [N,8] ----------------
// wave per node; head = lane>>3, f0 = (lane&7)*16; 8-lane group reduce.
__global__ __launch_bounds__(256) void scoresA(const ushort* __restrict__ xb,
                                               const float* __restrict__ v_s,
                                               const float* __restrict__ v_d,
                                               float* __restrict__ a1s,
                                               float* __restrict__ a1d, int N) {
    int node = blockIdx.x * 4 + (threadIdx.x >> 6);
    if (node >= N) return;
    int lane = threadIdx.x & 63;
    int head = lane >> 3, f0 = (lane & 7) * 16;
    const uint4* xp = (const uint4*)(xb + (size_t)node * 128 + f0);
    float xv[16];
    unpack8(xp[0], xv);
    unpack8(xp[1], xv + 8);
    const float4* sp = (const float4*)(v_s + head * 128 + f0);
    const float4* dp = (const float4*)(v_d + head * 128 + f0);
    float ps = 0.f, pd = 0.f;
#pragma unroll
    for (int q = 0; q < 4; ++q) {
        float4 s4 = sp[q], d4 = dp[q];
        ps += xv[q*4+0]*s4.x + xv[q*4+1]*s4.y + xv[q*4+2]*s4.z + xv[q*4+3]*s4.w;
        pd += xv[q*4+0]*d4.x + xv[q*4+1]*d4.y + xv[q*4+2]*d4.z + xv[q*4+3]*d4.w;
    }
#pragma unroll
    for (int off = 1; off < 8; off <<= 1) {
        ps += __shfl_xor(ps, off);
        pd += __shfl_xor(pd, off);
    }
    if ((lane & 7) == 0) {
        a1s[node * 8 + head] = ps;
        a1d[node * 8 + head] = pd;
    }
}

// ---------------- CSR build ----------------
__global__ void count_edges(const int* __restrict__ dst, int* cnt, int E) {
    int e = blockIdx.x * 256 + threadIdx.x;
    if (e < E) atomicAdd(&cnt[dst[e]], 1);
}

__global__ __launch_bounds__(1024) void scan_offsets(const int* cnt, int* row_start,
                                                     int* cursor, int N) {
    __shared__ int sm[1024];
    int t = threadIdx.x;
    int per = (N + 1023) / 1024;
    int beg = t * per;
    int end = beg + per; if (end > N) end = N;
    int sum = 0;
    for (int i = beg; i < end; ++i) sum += cnt[i];
    sm[t] = sum;
    __syncthreads();
    for (int off = 1; off < 1024; off <<= 1) {
        int add = (t >= off) ? sm[t - off] : 0;
        __syncthreads();
        sm[t] += add;
        __syncthreads();
    }
    int run = sm[t] - sum;
    for (int i = beg; i < end; ++i) {
        int c = cnt[i];
        row_start[i] = run;
        cursor[i] = run;
        run += c;
    }
    if (t == 1023) row_start[N] = run;
}

__global__ void fill_edges(const int* __restrict__ src, const int* __restrict__ dst,
                           int* cursor, int* __restrict__ srcs, int E) {
    int e = blockIdx.x * 256 + threadIdx.x;
    if (e < E) {
        int pos = atomicAdd(&cursor[dst[e]], 1);
        srcs[pos] = src[e];
    }
}

// ---------------- layer-1 aggregate in x-space: ax[N,8,128] bf16 ----------------
// wave per node; head = lane>>3, f0 = (lane&7)*16 (16 features, 16 fp32 acc).
// Duplicate x reads across the 8 head-groups dedup in the coalescer.
__global__ __launch_bounds__(256) void agg_x(const ushort* __restrict__ xb,
                                             const float* __restrict__ a1s,
                                             const float* __restrict__ a1d,
                                             const int* __restrict__ row_start,
                                             const int* __restrict__ srcs,
                                             ushort* __restrict__ ax, int N) {
    int node = blockIdx.x * 4 + (threadIdx.x >> 6);
    if (node >= N) return;
    int lane = threadIdx.x & 63;
    int head = lane >> 3, f0 = (lane & 7) * 16;
    int pbeg = row_start[node], pend = row_start[node + 1];
    float ad = a1d[node * 8 + head];
    float es = a1s[node * 8 + head] + ad;
    es = es > 0.f ? es : NEG_SLOPE * es;
    float ex_self = __expf(es);
    float den = ex_self;
    float acc[16];
    {
        const uint4* xp = (const uint4*)(xb + (size_t)node * 128 + f0);
        float xv[16];
        unpack8(xp[0], xv);
        unpack8(xp[1], xv + 8);
#pragma unroll
        for (int j = 0; j < 16; ++j) acc[j] = ex_self * xv[j];
    }
    for (int p = pbeg; p < pend; ++p) {
        int s = srcs[p];
        float e = a1s[s * 8 + head] + ad;
        e = e > 0.f ? e : NEG_SLOPE * e;
        float ex = __expf(e);
        den += ex;
        const uint4* xp = (const uint4*)(xb + (size_t)s * 128 + f0);
        float xv[16];
        unpack8(xp[0], xv);
        unpack8(xp[1], xv + 8);
#pragma unroll
        for (int j = 0; j < 16; ++j) acc[j] += ex * xv[j];
    }
    float rden = 1.0f / (den + 1e-16f);
    uint4 o0, o1;
    o0.x = pack2(acc[0] * rden, acc[1] * rden);
    o0.y = pack2(acc[2] * rden, acc[3] * rden);
    o0.z = pack2(acc[4] * rden, acc[5] * rden);
    o0.w = pack2(acc[6] * rden, acc[7] * rden);
    o1.x = pack2(acc[8] * rden, acc[9] * rden);
    o1.y = pack2(acc[10] * rden, acc[11] * rden);
    o1.z = pack2(acc[12] * rden, acc[13] * rden);
    o1.w = pack2(acc[14] * rden, acc[15] * rden);
    uint4* op = (uint4*)(ax + (size_t)node * 1024 + head * 128 + f0);
    op[0] = o0; op[1] = o1;
}

// ---------------- grouped GEMM: r1[n, h*64+c] = relu(ax[n,h,:]@W1_h^T + b1) ----
// block: 128 rows x 128 cols (= heads 2y, 2y+1). BK=32. bias+relu fused.
#define LDSB 40
__global__ __launch_bounds__(256) void gemm_grouped(const ushort* __restrict__ AX,
                                                    const ushort* __restrict__ W1b,
                                                    const float* __restrict__ b1,
                                                    ushort* __restrict__ r1,
                                                    int M) {
    __shared__ ushort As[2][128 * LDSB];
    __shared__ ushort Bs[128 * LDSB];
    int t = threadIdx.x;
    int wave = t >> 6, lane = t & 63;
    int quad = lane >> 4, l16 = lane & 15;
    int m0 = blockIdx.x * 128;
    int y = blockIdx.y;                 // cols [128y, 128y+128), heads 2y, 2y+1
    int wm = (wave & 1) * 64;
    int wn = (wave >> 1) * 64;
    int hsel = wn >> 6;                 // 0 or 1: which A tile this wave uses
    int srow = t >> 1;
    int sseg = (t & 1) * 16;
    f32x4 acc[4][4] = {};
    for (int k0 = 0; k0 < 128; k0 += 32) {
        uint4 a0v0, a0v1, a1v0, a1v1, bv0, bv1;
        {
            int grow = m0 + srow;
            if (grow < M) {
                const uint4* g0 = (const uint4*)(AX + (size_t)grow * 1024 + (2 * y) * 128 + k0 + sseg);
                const uint4* g1 = (const uint4*)(AX + (size_t)grow * 1024 + (2 * y + 1) * 128 + k0 + sseg);
                a0v0 = g0[0]; a0v1 = g0[1];
                a1v0 = g1[0]; a1v1 = g1[1];
            } else {
                a0v0 = make_uint4(0, 0, 0, 0); a0v1 = a0v0; a1v0 = a0v0; a1v1 = a0v0;
            }
            const uint4* gq = (const uint4*)(W1b + (size_t)(y * 128 + srow) * 128 + k0 + sseg);
            bv0 = gq[0]; bv1 = gq[1];
        }
        __syncthreads();
        *(uint4*)&As[0][srow * LDSB + sseg]     = a0v0;
        *(uint4*)&As[0][srow * LDSB + sseg + 8] = a0v1;
        *(uint4*)&As[1][srow * LDSB + sseg]     = a1v0;
        *(uint4*)&As[1][srow * LDSB + sseg + 8] = a1v1;
        *(uint4*)&Bs[srow * LDSB + sseg]        = bv0;
        *(uint4*)&Bs[srow * LDSB + sseg + 8]    = bv1;
        __syncthreads();
        bf16x8 af[4], bf[4];
#pragma unroll
        for (int i = 0; i < 4; ++i)
            af[i] = *(const bf16x8*)&As[hsel][(wm + i * 16 + l16) * LDSB + quad * 8];
#pragma unroll
        for (int j = 0; j < 4; ++j)
            bf[j] = *(const bf16x8*)&Bs[(wn + j * 16 + l16) * LDSB + quad * 8];
#pragma unroll
        for (int i = 0; i < 4; ++i)
#pragma unroll
            for (int j = 0; j < 4; ++j)
                acc[i][j] = __builtin_amdgcn_mfma_f32_16x16x32_bf16(
                    af[i], bf[j], acc[i][j], 0, 0, 0);
    }
#pragma unroll
    for (int i = 0; i < 4; ++i) {
#pragma unroll
        for (int r = 0; r < 4; ++r) {
            int grow = m0 + wm + i * 16 + quad * 4 + r;
            if (grow < M) {
#pragma unroll
                for (int j = 0; j < 4; ++j) {
                    int gcol = y * 128 + wn + j * 16 + l16;
                    float v = fmaxf(acc[i][j][r] + b1[gcol], 0.f);
                    r1[(size_t)grow * 512 + gcol] = f2bf(v);
                }
            }
        }
    }
}

// ---------------- MFMA GEMM (layer 2): C[M,N] = A[M,K]*B[N,K]^T, bf16 ----------
__global__ __launch_bounds__(256) void gemm_mfma(const ushort* __restrict__ A,
                                                 const ushort* __restrict__ B,
                                                 ushort* __restrict__ C,
                                                 int M, int N, int K) {
    __shared__ ushort As[128 * LDSB];
    __shared__ ushort Bs[128 * LDSB];
    int t = threadIdx.x;
    int wave = t >> 6, lane = t & 63;
    int quad = lane >> 4, l16 = lane & 15;
    int m0 = blockIdx.x * 128;
    int n0 = blockIdx.y * 128;
    int wm = (wave & 1) * 64;
    int wn = (wave >> 1) * 64;
    int srow = t >> 1;
    int sseg = (t & 1) * 16;
    f32x4 acc[4][4] = {};
    for (int k0 = 0; k0 < K; k0 += 32) {
        uint4 av0, av1, bv0, bv1;
        {
            int grow = m0 + srow;
            if (grow < M) {
                const uint4* gp = (const uint4*)(A + (size_t)grow * K + k0 + sseg);
                av0 = gp[0]; av1 = gp[1];
            } else {
                av0 = make_uint4(0, 0, 0, 0); av1 = av0;
            }
            const uint4* gq = (const uint4*)(B + (size_t)(n0 + srow) * K + k0 + sseg);
            bv0 = gq[0]; bv1 = gq[1];
        }
        __syncthreads();
        *(uint4*)&As[srow * LDSB + sseg]     = av0;
        *(uint4*)&As[srow * LDSB + sseg + 8] = av1;
        *(uint4*)&Bs[srow * LDSB + sseg]     = bv0;
        *(uint4*)&Bs[srow * LDSB + sseg + 8] = bv1;
        __syncthreads();
        bf16x8 af[4], bf[4];
#pragma unroll
        for (int i = 0; i < 4; ++i)
            af[i] = *(const bf16x8*)&As[(wm + i * 16 + l16) * LDSB + quad * 8];
#pragma unroll
        for (int j = 0; j < 4; ++j)
            bf[j] = *(const bf16x8*)&Bs[(wn + j * 16 + l16) * LDSB + quad * 8];
#pragma unroll
        for (int i = 0; i < 4; ++i)
#pragma unroll
            for (int j = 0; j < 4; ++j)
                acc[i][j] = __builtin_amdgcn_mfma_f32_16x16x32_bf16(
                    af[i], bf[j], acc[i][j], 0, 0, 0);
    }
#pragma unroll
    for (int i = 0; i < 4; ++i) {
#pragma unroll
        for (int r = 0; r < 4; ++r) {
            int grow = m0 + wm + i * 16 + quad * 4 + r;
            if (grow < M) {
#pragma unroll
                for (int j = 0; j < 4; ++j) {
                    int gcol = n0 + wn + j * 16 + l16;
                    C[(size_t)grow * N + gcol] = f2bf(acc[i][j][r]);
                }
            }
        }
    }
}

// ---------------- layer-2 scores ----------------
__global__ __launch_bounds__(256) void scores2(const ushort* __restrict__ h2,
                                               const float* __restrict__ att_s,
                                               const float* __restrict__ att_d,
                                               float* __restrict__ a2s,
                                               float* __restrict__ a2d, int N) {
    int node = blockIdx.x * 4 + (threadIdx.x >> 6);
    if (node >= N) return;
    int lane = threadIdx.x & 63;
    unsigned u = *(const unsigned*)(h2 + (size_t)node * 128 + lane * 2);
    float h0 = __uint_as_float(u << 16), h1v = __uint_as_float(u & 0xFFFF0000u);
    float2 s = *(const float2*)(att_s + lane * 2);
    float2 d = *(const float2*)(att_d + lane * 2);
    float ps = h0 * s.x + h1v * s.y;
    float pd = h0 * d.x + h1v * d.y;
#pragma unroll
    for (int off = 1; off < 64; off <<= 1) {
        ps += __shfl_xor(ps, off);
        pd += __shfl_xor(pd, off);
    }
    if (lane == 0) { a2s[node] = ps; a2d[node] = pd; }
}

// ---------------- layer-2 aggregate + bias + relu + fused pooling ----------------
// 2 nodes per wave (32 lanes, 4 features each); r2 never materialized.
__global__ __launch_bounds__(256) void agg2pool(const ushort* __restrict__ h2,
                                                const float* __restrict__ a2s,
                                                const float* __restrict__ a2d,
                                                const int* __restrict__ row_start,
                                                const int* __restrict__ srcs,
                                                const float* __restrict__ b2,
                                                const int* __restrict__ batch,
                                                const float* __restrict__ w_attn,
                                                const float* __restrict__ b_attn,
                                                const float* __restrict__ w_mask,
                                                const float* __restrict__ b_mask,
                                                float* pooled, int N) {
    int node = blockIdx.x * 8 + (threadIdx.x >> 5);
    if (node >= N) return;
    int sub = threadIdx.x & 31;
    int f0 = sub * 4;
    int pbeg = row_start[node], pend = row_start[node + 1];
    float ad = a2d[node];
    float es = a2s[node] + ad;
    es = es > 0.f ? es : NEG_SLOPE * es;
    float ex_self = __expf(es);
    float den = ex_self;
    float q[4];
    unpack4(*(const uint2*)(h2 + (size_t)node * 128 + f0), q);
    float acc[4];
#pragma unroll
    for (int j = 0; j < 4; ++j) acc[j] = ex_self * q[j];
    for (int p = pbeg; p < pend; ++p) {
        int s = srcs[p];
        float e = a2s[s] + ad;
        e = e > 0.f ? e : NEG_SLOPE * e;
        float ex = __expf(e);
        den += ex;
        float v[4];
        unpack4(*(const uint2*)(h2 + (size_t)s * 128 + f0), v);
#pragma unroll
        for (int j = 0; j < 4; ++j) acc[j] += ex * v[j];
    }
    float rden = 1.0f / (den + 1e-16f);
    float4 bv = *(const float4*)(b2 + f0);
    float o[4];
    o[0] = fmaxf(acc[0] * rden + bv.x, 0.f);
    o[1] = fmaxf(acc[1] * rden + bv.y, 0.f);
    o[2] = fmaxf(acc[2] * rden + bv.z, 0.f);
    o[3] = fmaxf(acc[3] * rden + bv.w, 0.f);
    // fused attention pooling: 32-lane reduce for the two dots
    float4 wa = *(const float4*)(w_attn + f0);
    float4 wm = *(const float4*)(w_mask + f0);
    float pa = o[0] * wa.x + o[1] * wa.y + o[2] * wa.z + o[3] * wa.w;
    float pm = o[0] * wm.x + o[1] * wm.y + o[2] * wm.z + o[3] * wm.w;
#pragma unroll
    for (int off = 1; off < 32; off <<= 1) {
        pa += __shfl_xor(pa, off);
        pm += __shfl_xor(pm, off);
    }
    float attn = pa + b_attn[0];
    float mask = 1.0f / (1.0f + __expf(-(pm + b_mask[0])));
    float w = attn * mask;
    int g = batch[node];
    float* pp = pooled + g * 128 + f0;
    atomicAdd(pp + 0, o[0] * w);
    atomicAdd(pp + 1, o[1] * w);
    atomicAdd(pp + 2, o[2] * w);
    atomicAdd(pp + 3, o[3] * w);
}

// ---------------- final tiny GEMM: out[256,2] ----------------
__global__ void final_kernel(const float* __restrict__ pooled,
                             const float* __restrict__ W_out,
                             const float* __restrict__ b_out,
                             float* __restrict__ out) {
    int tid = blockIdx.x * 256 + threadIdx.x;
    if (tid >= 512) return;
    int g = tid >> 1, o = tid & 1;
    const float* p = pooled + g * 128;
    const float* w = W_out + o * 128;
    float s = 0.f;
#pragma unroll 4
    for (int f = 0; f < 128; ++f) s += p[f] * w[f];
    out[tid] = s + b_out[o];
}

extern "C" void kernel_launch(void* const* d_in, const int* in_sizes, int n_in,
                              void* d_out, int out_size, void* d_ws, size_t ws_size,
                              hipStream_t stream) {
    const float* x        = (const float*)d_in[0];
    const int* edge_index = (const int*)d_in[1];
    const int* batch      = (const int*)d_in[2];
    const float* W1       = (const float*)d_in[3];
    const float* att_src1 = (const float*)d_in[4];
    const float* att_dst1 = (const float*)d_in[5];
    const float* b1       = (const float*)d_in[6];
    const float* W2       = (const float*)d_in[7];
    const float* att_src2 = (const float*)d_in[8];
    const float* att_dst2 = (const float*)d_in[9];
    const float* b2       = (const float*)d_in[10];
    const float* w_attn   = (const float*)d_in[11];
    const float* b_attn   = (const float*)d_in[12];
    const float* w_mask   = (const float*)d_in[13];
    const float* b_mask   = (const float*)d_in[14];
    const float* W_out    = (const float*)d_in[15];
    const float* b_out    = (const float*)d_in[16];
    float* out = (float*)d_out;

    int N = in_sizes[0] / 128;
    int E = in_sizes[1] / 2;
    const int* esrc = edge_index;
    const int* edst = edge_index + E;

    char* ws = (char*)d_ws;
    size_t off = 0;
    auto alloc = [&](size_t bytes) {
        void* p = ws + off;
        off = (off + bytes + 255) & ~(size_t)255;
        return p;
    };
    ushort* xb       = (ushort*)alloc((size_t)N * 128 * 2);    // bf16 x
    ushort* ax       = (ushort*)alloc((size_t)N * 1024 * 2);   // [N,8,128] bf16
    ushort* r1       = (ushort*)alloc((size_t)N * 512 * 2);    // bf16
    ushort* h2       = (ushort*)alloc((size_t)N * 128 * 2);    // bf16
    ushort* w1b      = (ushort*)alloc((size_t)512 * 128 * 2);
    ushort* w2b      = (ushort*)alloc((size_t)128 * 512 * 2);
    float*  v_s      = (float*)alloc((size_t)8 * 128 * 4);
    float*  v_d      = (float*)alloc((size_t)8 * 128 * 4);
    float*  a1s      = (float*)alloc((size_t)N * 8 * 4);
    float*  a1d      = (float*)alloc((size_t)N * 8 * 4);
    float*  a2s      = (float*)alloc((size_t)N * 4);
    float*  a2d      = (float*)alloc((size_t)N * 4);
    int*    row_start= (int*)alloc((size_t)(N + 1) * 4);
    int*    cursor   = (int*)alloc((size_t)N * 4);
    int*    srcs     = (int*)alloc((size_t)E * 4);
    float*  pooled   = (float*)alloc((size_t)256 * 128 * 4);

    hipMemsetAsync(cursor, 0, (size_t)N * 4, stream);
    hipMemsetAsync(pooled, 0, 256 * 128 * 4, stream);

    dim3 b256(256);
    // converts + score-vector prep
    int nx4 = N * 128 / 4;
    cvt_bf16<<<(nx4 + 255) / 256, b256, 0, stream>>>(x, xb, nx4);
    cvt_bf16<<<(512 * 128 / 4 + 255) / 256, b256, 0, stream>>>(W1, w1b, 512 * 128 / 4);
    cvt_bf16<<<(128 * 512 / 4 + 255) / 256, b256, 0, stream>>>(W2, w2b, 128 * 512 / 4);
    prep_v<<<4, b256, 0, stream>>>(W1, att_src1, att_dst1, v_s, v_d);
    scoresA<<<(N + 3) / 4, b256, 0, stream>>>(xb, v_s, v_d, a1s, a1d, N);
    // CSR build
    count_edges<<<(E + 255) / 256, b256, 0, stream>>>(edst, cursor, E);
    scan_offsets<<<1, 1024, 0, stream>>>(cursor, row_start, cursor, N);
    fill_edges<<<(E + 255) / 256, b256, 0, stream>>>(esrc, edst, cursor, srcs, E);
    // layer 1: aggregate x per head, then grouped GEMM (bias+relu fused)
    agg_x<<<(N + 3) / 4, b256, 0, stream>>>(xb, a1s, a1d, row_start, srcs, ax, N);
    gemm_grouped<<<dim3((N + 127) / 128, 4), b256, 0, stream>>>(ax, w1b, b1, r1, N);
    // layer 2
    gemm_mfma<<<dim3((N + 127) / 128, 1), b256, 0, stream>>>(r1, w2b, h2, N, 128, 512);
    scores2<<<(N + 3) / 4, b256, 0, stream>>>(h2, att_src2, att_dst2, a2s, a2d, N);
    agg2pool<<<(N + 7) / 8, b256, 0, stream>>>(h2, a2s, a2d, row_start, srcs, b2,
                                               batch, w_attn, b_attn, w_mask, b_mask,
                                               pooled, N);
    final_kernel<<<2, b256, 0, stream>>>(pooled, W_out, b_out, out);
}